// Round 1
// baseline (152.137 us; speedup 1.0000x reference)
//
#include <hip/hip_runtime.h>

#define T_LEN 262144
#define B_SZ 8
#define CHUNK 8192
#define HALO 4096
#define NTHREADS 512
#define ELEMS ((CHUNK + HALO) / NTHREADS)   // 24
#define SKIP_OFF (HALO / NTHREADS)          // 8
#define SKIP_ELEMS (CHUNK / NTHREADS)       // 16
#define CHUNKS_PER_ROW (T_LEN / CHUNK)      // 32
#define NBLOCKS (B_SZ * CHUNKS_PER_ROW)     // 256
#define LN256 5.5451774444795623f

__device__ __forceinline__ float frcp(float x) { return __builtin_amdgcn_rcpf(x); }
// tanh(x) = 1 - 2/(exp(2x)+1); robust for large |x| (exp->inf -> rcp->0 -> 1)
__device__ __forceinline__ float fast_tanh(float x) {
    float t = __expf(2.0f * x);
    return 1.0f - 2.0f * frcp(t + 1.0f);
}
__device__ __forceinline__ float fast_sigmoid(float x) {
    return frcp(1.0f + __expf(-x));
}
// monotonic float -> uint key for atomicMax
__device__ __forceinline__ unsigned int fkey(float f) {
    unsigned int u = __float_as_uint(f);
    return (u & 0x80000000u) ? ~u : (u | 0x80000000u);
}
__device__ __forceinline__ float funkey(unsigned int k) {
    unsigned int u = (k & 0x80000000u) ? (k & 0x7FFFFFFFu) : ~k;
    return __uint_as_float(u);
}

// One dilation cycle (10 layers, d = 1..512). STAGE 0 also applies the causal
// conv to x; STAGE 2 skips the h write and fuses the epilogue (conv1/conv2/
// mu-law) + per-row max reduction.
template <int STAGE>
__global__ __launch_bounds__(NTHREADS)
void stage_kernel(const float* __restrict__ in,
                  const float* __restrict__ cw, const float* __restrict__ cb,
                  const float* __restrict__ fw, const float* __restrict__ fb,
                  const float* __restrict__ gw, const float* __restrict__ gb,
                  const float* __restrict__ rw, const float* __restrict__ rb,
                  float* __restrict__ hout,
                  float* __restrict__ skio,
                  const float* __restrict__ c1w, const float* __restrict__ c1b,
                  const float* __restrict__ c2w, const float* __restrict__ c2b,
                  unsigned int* __restrict__ rowmax)
{
    __shared__ float buf[2][CHUNK + HALO];   // 96 KB double buffer
    __shared__ float red[NTHREADS / 64];

    const int tid = threadIdx.x;
    const int bid = blockIdx.x;
    const int row = bid / CHUNKS_PER_ROW;
    const int chunk = bid % CHUNKS_PER_ROW;
    const int rowbase = row * T_LEN;
    const int base_t = chunk * CHUNK;

    // ---- load input (x or h) incl. halo; zero at t<0 ----
    #pragma unroll
    for (int i = 0; i < ELEMS; ++i) {
        int idx = tid + i * NTHREADS;
        int t = base_t - HALO + idx;
        buf[0][idx] = (t >= 0) ? in[rowbase + t] : 0.0f;
    }

    // ---- skip accumulator (registers) ----
    float sk[SKIP_ELEMS];
    #pragma unroll
    for (int s = 0; s < SKIP_ELEMS; ++s) {
        if (STAGE == 0) sk[s] = 0.0f;
        else            sk[s] = skio[rowbase + base_t + s * NTHREADS + tid];
    }
    __syncthreads();

    int cur = 0;
    if (STAGE == 0) {
        // causal conv, d = 1
        float w[5];
        #pragma unroll
        for (int j = 0; j < 5; ++j) w[j] = cw[4 - j];
        const float bb = cb[0];
        #pragma unroll
        for (int i = 0; i < ELEMS; ++i) {
            int idx = tid + i * NTHREADS;
            float acc = bb;
            #pragma unroll
            for (int j = 0; j < 5; ++j) {
                int ii = idx - j;
                if (i == 0) ii = (ii < 0) ? 0 : ii;  // clamp; value irrelevant (halo junk zone)
                acc += w[j] * buf[0][ii];
            }
            int t = base_t - HALO + idx;
            buf[1][idx] = (t >= 0) ? acc : 0.0f;
        }
        __syncthreads();
        cur = 1;
    }

    // ---- 10 dilated gated layers ----
    for (int k = 0; k < 10; ++k) {
        const int L = STAGE * 10 + k;
        const int d = 1 << k;
        float wf[5], wg[5];
        #pragma unroll
        for (int j = 0; j < 5; ++j) {
            wf[j] = fw[L * 5 + 4 - j];   // tap offset j*d uses original weight index 4-j
            wg[j] = gw[L * 5 + 4 - j];
        }
        const float fbv = fb[L], gbv = gb[L], rwv = rw[L], rbv = rb[L];
        const float* __restrict__ src = buf[cur & 1];
        float* __restrict__ dst = buf[(cur & 1) ^ 1];
        #pragma unroll
        for (int i = 0; i < ELEMS; ++i) {
            const int idx = tid + i * NTHREADS;
            float h0 = src[idx];
            float af = wf[0] * h0 + fbv;
            float ag = wg[0] * h0 + gbv;
            #pragma unroll
            for (int j = 1; j < 5; ++j) {
                int ii = idx - j * d;
                if (i < 4) ii = (ii < 0) ? 0 : ii;   // only idx<2048 can underflow (d<=512)
                float v = src[ii];
                af += wf[j] * v;
                ag += wg[j] * v;
            }
            float f = fast_tanh(af);
            float g = fast_sigmoid(ag);
            float o = f * g;
            float nh = rwv * o + rbv + h0;
            int t = base_t - HALO + idx;
            if (t < 0) nh = 0.0f;                    // keep t<0 padding exactly zero per layer
            dst[idx] = nh;
            if (i >= SKIP_OFF) sk[i - SKIP_OFF] += o;
        }
        __syncthreads();
        cur ^= 1;
    }

    if (STAGE < 2) {
        const float* src = buf[cur & 1];
        #pragma unroll
        for (int s = 0; s < SKIP_ELEMS; ++s) {
            int g = rowbase + base_t + s * NTHREADS + tid;
            hout[g] = src[HALO + s * NTHREADS + tid];
            skio[g] = sk[s];
        }
    } else {
        // fused epilogue: conv1 -> relu -> conv2 -> relu -> mu-law expand
        const float c1wv = c1w[0], c1bv = c1b[0], c2wv = c2w[0], c2bv = c2b[0];
        float pmax = -3.0e38f;
        #pragma unroll
        for (int s = 0; s < SKIP_ELEMS; ++s) {
            float v = sk[s];
            float a  = c1wv * fmaxf(v, 0.0f) + c1bv;
            float b2 = c2wv * fmaxf(a, 0.0f) + c2bv;
            float ab = fabsf(b2);
            float m  = __expf(ab * LN256) - 1.0f;
            float p  = copysignf(m * (1.0f / 255.0f), b2);
            skio[rowbase + base_t + s * NTHREADS + tid] = p;
            pmax = fmaxf(pmax, p);
        }
        #pragma unroll
        for (int off = 32; off > 0; off >>= 1)
            pmax = fmaxf(pmax, __shfl_down(pmax, off, 64));
        if ((tid & 63) == 0) red[tid >> 6] = pmax;
        __syncthreads();
        if (tid == 0) {
            float mm = red[0];
            #pragma unroll
            for (int w2 = 1; w2 < NTHREADS / 64; ++w2) mm = fmaxf(mm, red[w2]);
            atomicMax(rowmax + row, fkey(mm));
        }
    }
}

__global__ __launch_bounds__(NTHREADS)
void sumexp_kernel(const float* __restrict__ p,
                   const unsigned int* __restrict__ rowmax,
                   float* __restrict__ rowsum)
{
    __shared__ float red[NTHREADS / 64];
    const int tid = threadIdx.x;
    const int bid = blockIdx.x;
    const int row = bid / CHUNKS_PER_ROW;
    const int base = row * T_LEN + (bid % CHUNKS_PER_ROW) * CHUNK;
    const float mx = funkey(rowmax[row]);
    float acc = 0.0f;
    #pragma unroll
    for (int s = 0; s < SKIP_ELEMS; ++s)
        acc += __expf(p[base + s * NTHREADS + tid] - mx);
    #pragma unroll
    for (int off = 32; off > 0; off >>= 1)
        acc += __shfl_down(acc, off, 64);
    if ((tid & 63) == 0) red[tid >> 6] = acc;
    __syncthreads();
    if (tid == 0) {
        float s2 = 0.0f;
        #pragma unroll
        for (int w = 0; w < NTHREADS / 64; ++w) s2 += red[w];
        atomicAdd(rowsum + row, s2);
    }
}

__global__ __launch_bounds__(NTHREADS)
void norm_kernel(float* __restrict__ p,
                 const unsigned int* __restrict__ rowmax,
                 const float* __restrict__ rowsum)
{
    const int tid = threadIdx.x;
    const int bid = blockIdx.x;
    const int row = bid / CHUNKS_PER_ROW;
    const int base = row * T_LEN + (bid % CHUNKS_PER_ROW) * CHUNK;
    const float mx = funkey(rowmax[row]);
    const float inv = 1.0f / rowsum[row];
    #pragma unroll
    for (int s = 0; s < SKIP_ELEMS; ++s) {
        int g = base + s * NTHREADS + tid;
        p[g] = __expf(p[g] - mx) * inv;
    }
}

__global__ void init_stats(unsigned int* rowmax, float* rowsum)
{
    int i = threadIdx.x;
    if (i < B_SZ) { rowmax[i] = 0u; rowsum[i] = 0.0f; }
}

extern "C" void kernel_launch(void* const* d_in, const int* in_sizes, int n_in,
                              void* d_out, int out_size, void* d_ws, size_t ws_size,
                              hipStream_t stream)
{
    (void)in_sizes; (void)n_in; (void)out_size; (void)ws_size;
    const float* x   = (const float*)d_in[0];
    const float* cw  = (const float*)d_in[1];
    const float* cb  = (const float*)d_in[2];
    const float* fw  = (const float*)d_in[3];
    const float* fb  = (const float*)d_in[4];
    const float* gw  = (const float*)d_in[5];
    const float* gb  = (const float*)d_in[6];
    const float* rw  = (const float*)d_in[7];
    const float* rb  = (const float*)d_in[8];
    const float* c1w = (const float*)d_in[9];
    const float* c1b = (const float*)d_in[10];
    const float* c2w = (const float*)d_in[11];
    const float* c2b = (const float*)d_in[12];
    float* out = (float*)d_out;

    const size_t NTOT = (size_t)B_SZ * T_LEN;
    float* hA = (float*)d_ws;                                   // 8 MB
    float* hB = (float*)((char*)d_ws + NTOT * 4);               // 8 MB
    unsigned int* rowmax = (unsigned int*)((char*)d_ws + 2 * NTOT * 4);
    float* rowsum = (float*)((char*)d_ws + 2 * NTOT * 4 + 64);

    init_stats<<<1, 64, 0, stream>>>(rowmax, rowsum);
    // d_out doubles as the skip accumulator between stages, then holds
    // pre-softmax values, then the final softmax output.
    stage_kernel<0><<<NBLOCKS, NTHREADS, 0, stream>>>(x,  cw, cb, fw, fb, gw, gb, rw, rb,
                                                      hA, out, c1w, c1b, c2w, c2b, rowmax);
    stage_kernel<1><<<NBLOCKS, NTHREADS, 0, stream>>>(hA, cw, cb, fw, fb, gw, gb, rw, rb,
                                                      hB, out, c1w, c1b, c2w, c2b, rowmax);
    stage_kernel<2><<<NBLOCKS, NTHREADS, 0, stream>>>(hB, cw, cb, fw, fb, gw, gb, rw, rb,
                                                      nullptr, out, c1w, c1b, c2w, c2b, rowmax);
    sumexp_kernel<<<NBLOCKS, NTHREADS, 0, stream>>>(out, rowmax, rowsum);
    norm_kernel<<<NBLOCKS, NTHREADS, 0, stream>>>(out, rowmax, rowsum);
}

// Round 2
// 104.626 us; speedup vs baseline: 1.4541x; 1.4541x over previous
//
#include <hip/hip_runtime.h>

#define T_LEN 262144
#define B_SZ 8
#define CHUNK 8192
#define HALO 4096
#define NTHREADS 1024
#define ELEMS ((CHUNK + HALO) / NTHREADS)   // 12
#define SKIP_OFF (HALO / NTHREADS)          // 4
#define SKIP_ELEMS (CHUNK / NTHREADS)       // 8
#define CHUNKS_PER_ROW (T_LEN / CHUNK)      // 32
#define NBLOCKS (B_SZ * CHUNKS_PER_ROW)     // 256
#define LN256 5.5451774444795623f
#define NEG2LOG2E (-2.8853900817779268f)
#define NEGLOG2E  (-1.4426950408889634f)

__device__ __forceinline__ float frcp(float x) { return __builtin_amdgcn_rcpf(x); }
__device__ __forceinline__ float fexp2(float x) { return __builtin_amdgcn_exp2f(x); }
// monotonic float -> uint key for atomicMax
__device__ __forceinline__ unsigned int fkey(float f) {
    unsigned int u = __float_as_uint(f);
    return (u & 0x80000000u) ? ~u : (u | 0x80000000u);
}
__device__ __forceinline__ float funkey(unsigned int k) {
    unsigned int u = (k & 0x80000000u) ? (k & 0x7FFFFFFFu) : ~k;
    return __uint_as_float(u);
}

// One dilation cycle (10 layers, d = 1..512). STAGE 0 also applies the causal
// conv to x; STAGE 2 skips the h write and fuses the epilogue (conv1/conv2/
// mu-law) + per-row max reduction.
//
// Layout invariant: element idx = tid + i*NTHREADS, and since
// HALO == 4*NTHREADS, "global t < 0" <=> (chunk==0 && i < 4): the padding
// mask is compile-time per i, runtime-uniform per block.
template <int STAGE>
__global__ __launch_bounds__(NTHREADS, 4)
void stage_kernel(const float* __restrict__ in,
                  const float* __restrict__ cw, const float* __restrict__ cb,
                  const float* __restrict__ fw, const float* __restrict__ fb,
                  const float* __restrict__ gw, const float* __restrict__ gb,
                  const float* __restrict__ rw, const float* __restrict__ rb,
                  float* __restrict__ hout,
                  float* __restrict__ skio,
                  const float* __restrict__ c1w, const float* __restrict__ c1b,
                  const float* __restrict__ c2w, const float* __restrict__ c2b,
                  unsigned int* __restrict__ rowmax)
{
    __shared__ float buf[2][CHUNK + HALO];   // 96 KB double buffer
    __shared__ float red[NTHREADS / 64];

    const int tid = threadIdx.x;
    const int bid = blockIdx.x;
    const int row = bid / CHUNKS_PER_ROW;
    const int chunk = bid % CHUNKS_PER_ROW;
    const int rowbase = row * T_LEN;
    const int base_t = chunk * CHUNK;
    const bool first = (chunk == 0);

    // ---- load input (x or h) incl. halo, float4; zero at t<0 (first, g==0) ----
    #pragma unroll
    for (int g = 0; g < (CHUNK + HALO) / (4 * NTHREADS); ++g) {   // 3
        int idx4 = tid * 4 + g * 4 * NTHREADS;
        int t = base_t - HALO + idx4;
        float4 v;
        if (first && g == 0) v = make_float4(0.f, 0.f, 0.f, 0.f);
        else                 v = *(const float4*)(in + rowbase + t);
        *(float4*)(&buf[0][idx4]) = v;
    }

    // ---- skip accumulator (registers) ----
    float sk[SKIP_ELEMS];
    #pragma unroll
    for (int s = 0; s < SKIP_ELEMS; ++s) {
        if (STAGE == 0) sk[s] = 0.0f;
        else            sk[s] = skio[rowbase + base_t + s * NTHREADS + tid];
    }
    __syncthreads();

    int cur = 0;
    if (STAGE == 0) {
        // causal conv, d = 1
        float w[5];
        #pragma unroll
        for (int j = 0; j < 5; ++j) w[j] = cw[4 - j];
        const float bb = cb[0];
        #pragma unroll
        for (int i = 0; i < ELEMS; ++i) {
            int idx = tid + i * NTHREADS;
            float acc = bb;
            #pragma unroll
            for (int j = 0; j < 5; ++j) {
                int ii = idx - j;
                if (i == 0) ii = (ii < 0) ? 0 : ii;  // clamp; value irrelevant (halo junk)
                acc += w[j] * buf[0][ii];
            }
            if (i < 4 && first) acc = 0.0f;          // t<0 padding
            buf[1][idx] = acc;
        }
        __syncthreads();
        cur = 1;
    }

    // ---- 10 dilated gated layers ----
    for (int k = 0; k < 10; ++k) {
        const int L = STAGE * 10 + k;
        const int d = 1 << k;
        // pre-scale so activations use exp2 directly:
        //   tanh(a)    = (1 - e^{-2a}) / (1 + e^{-2a}),  E1 = exp2(-2*log2e * a)
        //   sigmoid(b) = 1 / (1 + e^{-b}),               E2 = exp2(-log2e * b)
        //   o = (1 - E1) * rcp((1 + E1) * (1 + E2))
        float wf[5], wg[5];
        #pragma unroll
        for (int j = 0; j < 5; ++j) {
            wf[j] = fw[L * 5 + 4 - j] * NEG2LOG2E;  // tap j*d uses weight index 4-j
            wg[j] = gw[L * 5 + 4 - j] * NEGLOG2E;
        }
        const float fbv = fb[L] * NEG2LOG2E, gbv = gb[L] * NEGLOG2E;
        const float rwv = rw[L], rbv = rb[L];
        const float* __restrict__ src = buf[cur & 1];
        float* __restrict__ dst = buf[(cur & 1) ^ 1];
        #pragma unroll
        for (int i = 0; i < ELEMS; ++i) {
            const int idx = tid + i * NTHREADS;
            float h0 = src[idx];
            float af = __builtin_fmaf(wf[0], h0, fbv);
            float ag = __builtin_fmaf(wg[0], h0, gbv);
            #pragma unroll
            for (int j = 1; j < 5; ++j) {
                int ii = idx - j * d;
                if (i < 2) ii = (ii < 0) ? 0 : ii;   // only idx<2048 can underflow
                float v = src[ii];
                af = __builtin_fmaf(wf[j], v, af);
                ag = __builtin_fmaf(wg[j], v, ag);
            }
            float E1 = fexp2(af);
            float E2 = fexp2(ag);
            float d1 = 1.0f + E1;
            float den = __builtin_fmaf(E2, d1, d1);
            float o = (1.0f - E1) * frcp(den);
            float nh = __builtin_fmaf(rwv, o, h0 + rbv);
            if (i < 4 && first) nh = 0.0f;           // keep t<0 padding exactly zero
            dst[idx] = nh;
            if (i >= SKIP_OFF) sk[i - SKIP_OFF] += o;
        }
        __syncthreads();
        cur ^= 1;
    }

    if (STAGE < 2) {
        const float* src = buf[cur & 1];
        #pragma unroll
        for (int g = 0; g < CHUNK / (4 * NTHREADS); ++g) {        // 2
            int idx4 = tid * 4 + g * 4 * NTHREADS;
            float4 v = *(const float4*)(&src[HALO + idx4]);
            *(float4*)(hout + rowbase + base_t + idx4) = v;
        }
        #pragma unroll
        for (int s = 0; s < SKIP_ELEMS; ++s)
            skio[rowbase + base_t + s * NTHREADS + tid] = sk[s];
    } else {
        // fused epilogue: conv1 -> relu -> conv2 -> relu -> mu-law expand
        const float c1wv = c1w[0], c1bv = c1b[0], c2wv = c2w[0], c2bv = c2b[0];
        float pmax = -3.0e38f;
        #pragma unroll
        for (int s = 0; s < SKIP_ELEMS; ++s) {
            float v = sk[s];
            float a  = __builtin_fmaf(c1wv, fmaxf(v, 0.0f), c1bv);
            float b2 = __builtin_fmaf(c2wv, fmaxf(a, 0.0f), c2bv);
            float ab = fabsf(b2);
            float m  = __expf(ab * LN256) - 1.0f;
            float p  = copysignf(m * (1.0f / 255.0f), b2);
            skio[rowbase + base_t + s * NTHREADS + tid] = p;
            pmax = fmaxf(pmax, p);
        }
        #pragma unroll
        for (int off = 32; off > 0; off >>= 1)
            pmax = fmaxf(pmax, __shfl_down(pmax, off, 64));
        if ((tid & 63) == 0) red[tid >> 6] = pmax;
        __syncthreads();
        if (tid == 0) {
            float mm = red[0];
            #pragma unroll
            for (int w2 = 1; w2 < NTHREADS / 64; ++w2) mm = fmaxf(mm, red[w2]);
            atomicMax(rowmax + row, fkey(mm));
        }
    }
}

__global__ __launch_bounds__(NTHREADS)
void sumexp_kernel(const float* __restrict__ p,
                   const unsigned int* __restrict__ rowmax,
                   float* __restrict__ rowsum)
{
    __shared__ float red[NTHREADS / 64];
    const int tid = threadIdx.x;
    const int bid = blockIdx.x;
    const int row = bid / CHUNKS_PER_ROW;
    const int base = row * T_LEN + (bid % CHUNKS_PER_ROW) * CHUNK;
    const float mx = funkey(rowmax[row]);
    float acc = 0.0f;
    #pragma unroll
    for (int s = 0; s < SKIP_ELEMS; ++s)
        acc += __expf(p[base + s * NTHREADS + tid] - mx);
    #pragma unroll
    for (int off = 32; off > 0; off >>= 1)
        acc += __shfl_down(acc, off, 64);
    if ((tid & 63) == 0) red[tid >> 6] = acc;
    __syncthreads();
    if (tid == 0) {
        float s2 = 0.0f;
        #pragma unroll
        for (int w = 0; w < NTHREADS / 64; ++w) s2 += red[w];
        atomicAdd(rowsum + row, s2);
    }
}

__global__ __launch_bounds__(NTHREADS)
void norm_kernel(float* __restrict__ p,
                 const unsigned int* __restrict__ rowmax,
                 const float* __restrict__ rowsum)
{
    const int tid = threadIdx.x;
    const int bid = blockIdx.x;
    const int row = bid / CHUNKS_PER_ROW;
    const int base = row * T_LEN + (bid % CHUNKS_PER_ROW) * CHUNK;
    const float mx = funkey(rowmax[row]);
    const float inv = 1.0f / rowsum[row];
    #pragma unroll
    for (int s = 0; s < SKIP_ELEMS; ++s) {
        int g = base + s * NTHREADS + tid;
        p[g] = __expf(p[g] - mx) * inv;
    }
}

__global__ void init_stats(unsigned int* rowmax, float* rowsum)
{
    int i = threadIdx.x;
    if (i < B_SZ) { rowmax[i] = 0u; rowsum[i] = 0.0f; }
}

extern "C" void kernel_launch(void* const* d_in, const int* in_sizes, int n_in,
                              void* d_out, int out_size, void* d_ws, size_t ws_size,
                              hipStream_t stream)
{
    (void)in_sizes; (void)n_in; (void)out_size; (void)ws_size;
    const float* x   = (const float*)d_in[0];
    const float* cw  = (const float*)d_in[1];
    const float* cb  = (const float*)d_in[2];
    const float* fw  = (const float*)d_in[3];
    const float* fb  = (const float*)d_in[4];
    const float* gw  = (const float*)d_in[5];
    const float* gb  = (const float*)d_in[6];
    const float* rw  = (const float*)d_in[7];
    const float* rb  = (const float*)d_in[8];
    const float* c1w = (const float*)d_in[9];
    const float* c1b = (const float*)d_in[10];
    const float* c2w = (const float*)d_in[11];
    const float* c2b = (const float*)d_in[12];
    float* out = (float*)d_out;

    const size_t NTOT = (size_t)B_SZ * T_LEN;
    float* hA = (float*)d_ws;                                   // 8 MB
    float* hB = (float*)((char*)d_ws + NTOT * 4);               // 8 MB
    unsigned int* rowmax = (unsigned int*)((char*)d_ws + 2 * NTOT * 4);
    float* rowsum = (float*)((char*)d_ws + 2 * NTOT * 4 + 64);

    init_stats<<<1, 64, 0, stream>>>(rowmax, rowsum);
    // d_out doubles as the skip accumulator between stages, then holds
    // pre-softmax values, then the final softmax output.
    stage_kernel<0><<<NBLOCKS, NTHREADS, 0, stream>>>(x,  cw, cb, fw, fb, gw, gb, rw, rb,
                                                      hA, out, c1w, c1b, c2w, c2b, rowmax);
    stage_kernel<1><<<NBLOCKS, NTHREADS, 0, stream>>>(hA, cw, cb, fw, fb, gw, gb, rw, rb,
                                                      hB, out, c1w, c1b, c2w, c2b, rowmax);
    stage_kernel<2><<<NBLOCKS, NTHREADS, 0, stream>>>(hB, cw, cb, fw, fb, gw, gb, rw, rb,
                                                      nullptr, out, c1w, c1b, c2w, c2b, rowmax);
    sumexp_kernel<<<NBLOCKS, NTHREADS, 0, stream>>>(out, rowmax, rowsum);
    norm_kernel<<<NBLOCKS, NTHREADS, 0, stream>>>(out, rowmax, rowsum);
}

// Round 3
// 95.489 us; speedup vs baseline: 1.5932x; 1.0957x over previous
//
#include <hip/hip_runtime.h>

#define T_LEN 262144
#define B_SZ 8
#define CHUNK 8192
#define HALO 4096
#define NTHREADS 1024
#define NGROUPW 3                      // float4 groups per thread: 12288/4/1024
#define CHUNKS_PER_ROW (T_LEN / CHUNK) // 32
#define NBLOCKS (B_SZ * CHUNKS_PER_ROW)
#define LOG2E 1.4426950408889634f
#define NEG2LOG2E (-2.8853900817779268f)
#define NEGLOG2E  (-1.4426950408889634f)

__device__ __forceinline__ float frcp(float x)  { return __builtin_amdgcn_rcpf(x); }
__device__ __forceinline__ float fexp2(float x) { return __builtin_amdgcn_exp2f(x); }
__device__ __forceinline__ float4 ld4(const float* p) { return *(const float4*)p; }
__device__ __forceinline__ void st4(float* p, float4 v) { *(float4*)p = v; }
__device__ __forceinline__ float4 f4(float v) { return make_float4(v, v, v, v); }
__device__ __forceinline__ float4 fma4(float a, float4 b, float4 c) {
    return make_float4(__builtin_fmaf(a, b.x, c.x), __builtin_fmaf(a, b.y, c.y),
                       __builtin_fmaf(a, b.z, c.z), __builtin_fmaf(a, b.w, c.w));
}
__device__ __forceinline__ float4 add4(float4 a, float4 b) {
    return make_float4(a.x + b.x, a.y + b.y, a.z + b.z, a.w + b.w);
}
// o = tanh(a)*sigmoid(b) with af = -2*log2e*a, ag = -log2e*b pre-scaled:
// E1=2^af=e^{-2a}, E2=2^ag=e^{-b}; o = (1-E1) / ((1+E1)(1+E2))
__device__ __forceinline__ float gate1(float af, float ag) {
    float E1 = fexp2(af), E2 = fexp2(ag);
    float d1 = 1.0f + E1;
    float den = __builtin_fmaf(E2, d1, d1);
    return (1.0f - E1) * frcp(den);
}
__device__ __forceinline__ float4 resid4(float rwv, float4 o, float4 hw, float rbv) {
    return make_float4(__builtin_fmaf(rwv, o.x, hw.x + rbv), __builtin_fmaf(rwv, o.y, hw.y + rbv),
                       __builtin_fmaf(rwv, o.z, hw.z + rbv), __builtin_fmaf(rwv, o.w, hw.w + rbv));
}
// conv1->relu->conv2->relu->mu-law expand; exp(|b|*ln256) == exp2(|b|*8)
__device__ __forceinline__ float mulaw(float v, float c1wv, float c1bv, float c2wv, float c2bv) {
    float a  = __builtin_fmaf(c1wv, fmaxf(v, 0.0f), c1bv);
    float b2 = __builtin_fmaf(c2wv, fmaxf(a, 0.0f), c2bv);
    float m  = fexp2(fabsf(b2) * 8.0f) - 1.0f;
    return copysignf(m * (1.0f / 255.0f), b2);
}

// One dilation cycle (10 layers, d=1..512). Thread owns 3 float4 groups
// (elements 4*tid+w*4096 .. +3) IN REGISTERS across all layers; LDS is a
// single in-place buffer used only for cross-thread taps (b128 reads).
// Layer = {read taps, compute} -> barrier -> {write own groups} -> barrier.
// Zero-padding invariant: global t<0 <=> (chunk==0 && w==0).
template <int STAGE>
__global__ __launch_bounds__(NTHREADS, 4)
void stage_kernel(const float* __restrict__ in,
                  const float* __restrict__ cw, const float* __restrict__ cb,
                  const float* __restrict__ fw, const float* __restrict__ fb,
                  const float* __restrict__ gw, const float* __restrict__ gb,
                  const float* __restrict__ rw, const float* __restrict__ rb,
                  float* __restrict__ hout, float* __restrict__ skio,
                  const float* __restrict__ c1w, const float* __restrict__ c1b,
                  const float* __restrict__ c2w, const float* __restrict__ c2b,
                  float2* __restrict__ blockstats)
{
    __shared__ float lds[CHUNK + HALO];      // 48 KB, single buffer
    __shared__ float red[NTHREADS / 64];

    const int tid = threadIdx.x;
    const int bid = blockIdx.x;
    const int row = bid / CHUNKS_PER_ROW;
    const int chunk = bid % CHUNKS_PER_ROW;
    const int rowbase = row * T_LEN;
    const int base_t = chunk * CHUNK;
    const bool first = (chunk == 0);
    const float* inb = in + rowbase + base_t - HALO;

    // ---- load own groups (regs) + fill LDS ----
    float4 h[NGROUPW];
    #pragma unroll
    for (int w = 0; w < NGROUPW; ++w) {
        int idx4 = 4 * tid + w * (4 * NTHREADS);
        if (w == 0 && first) h[w] = f4(0.0f);
        else                 h[w] = ld4(inb + idx4);
        st4(&lds[idx4], h[w]);
    }
    float4 sk1, sk2;   // skip accumulators for w=1,2 (valid region)
    if (STAGE == 0) { sk1 = f4(0.0f); sk2 = f4(0.0f); }
    else {
        sk1 = ld4(skio + rowbase + base_t + 4 * tid);
        sk2 = ld4(skio + rowbase + base_t + 4096 + 4 * tid);
    }
    __syncthreads();

    if (STAGE == 0) {
        // causal conv (d=1, taps j=0..4, weight for distance m is cw[4-m])
        const float c0 = cw[4], c1 = cw[3], c2 = cw[2], c3 = cw[1], c4 = cw[0];
        const float bb = cb[0];
        #pragma unroll
        for (int w = 0; w < NGROUPW; ++w) {
            int G = tid + w * NTHREADS;
            int gm = G - 1; gm = gm < 0 ? 0 : gm;
            float4 T = ld4(&lds[4 * gm]);
            float4 hw = h[w];
            float4 t1 = make_float4(T.w, hw.x, hw.y, hw.z);
            float4 t2 = make_float4(T.z, T.w, hw.x, hw.y);
            float4 t3 = make_float4(T.y, T.z, T.w, hw.x);
            float4 t4 = make_float4(T.x, T.y, T.z, T.w);
            float4 acc = fma4(c0, hw, f4(bb));
            acc = fma4(c1, t1, acc);
            acc = fma4(c2, t2, acc);
            acc = fma4(c3, t3, acc);
            acc = fma4(c4, t4, acc);
            if (w == 0 && first) acc = f4(0.0f);
            h[w] = acc;
        }
        __syncthreads();
        #pragma unroll
        for (int w = 0; w < NGROUPW; ++w) st4(&lds[4 * (tid + w * NTHREADS)], h[w]);
        __syncthreads();
    }

    // ---- 10 dilated gated layers, fully unrolled (d compile-time) ----
    #pragma unroll
    for (int k = 0; k < 10; ++k) {
        const int d = 1 << k;
        const int L = STAGE * 10 + k;
        const float* fwL = fw + 5 * L;
        const float* gwL = gw + 5 * L;
        const float wf0 = fwL[4] * NEG2LOG2E, wf1 = fwL[3] * NEG2LOG2E,
                    wf2 = fwL[2] * NEG2LOG2E, wf3 = fwL[1] * NEG2LOG2E,
                    wf4 = fwL[0] * NEG2LOG2E;
        const float wg0 = gwL[4] * NEGLOG2E, wg1 = gwL[3] * NEGLOG2E,
                    wg2 = gwL[2] * NEGLOG2E, wg3 = gwL[1] * NEGLOG2E,
                    wg4 = gwL[0] * NEGLOG2E;
        const float fbv = fb[L] * NEG2LOG2E, gbv = gb[L] * NEGLOG2E;
        const float rwv = rw[L], rbv = rb[L];

        #pragma unroll
        for (int w = 0; w < NGROUPW; ++w) {
            const int G = tid + w * NTHREADS;
            float4 hw = h[w];
            float4 t1, t2, t3, t4;
            if (d >= 4) {
                const int DG = d >> 2;           // taps stay float4-aligned
                int g1 = G - DG;     g1 = g1 < 0 ? 0 : g1;
                int g2 = G - 2 * DG; g2 = g2 < 0 ? 0 : g2;
                int g3 = G - 3 * DG; g3 = g3 < 0 ? 0 : g3;
                int g4 = G - 4 * DG; g4 = g4 < 0 ? 0 : g4;
                t1 = ld4(&lds[4 * g1]);
                t2 = ld4(&lds[4 * g2]);
                t3 = ld4(&lds[4 * g3]);
                t4 = ld4(&lds[4 * g4]);
            } else if (d == 1) {
                int gm = G - 1; gm = gm < 0 ? 0 : gm;
                float4 T = ld4(&lds[4 * gm]);
                t1 = make_float4(T.w, hw.x, hw.y, hw.z);
                t2 = make_float4(T.z, T.w, hw.x, hw.y);
                t3 = make_float4(T.y, T.z, T.w, hw.x);
                t4 = make_float4(T.x, T.y, T.z, T.w);
            } else { // d == 2
                int gm1 = G - 1; gm1 = gm1 < 0 ? 0 : gm1;
                int gm2 = G - 2; gm2 = gm2 < 0 ? 0 : gm2;
                float4 T1 = ld4(&lds[4 * gm1]);
                float4 T2 = ld4(&lds[4 * gm2]);
                t1 = make_float4(T1.z, T1.w, hw.x, hw.y);
                t2 = T1;
                t3 = make_float4(T2.z, T2.w, T1.x, T1.y);
                t4 = T2;
            }
            float4 af = fma4(wf0, hw, f4(fbv));
            af = fma4(wf1, t1, af); af = fma4(wf2, t2, af);
            af = fma4(wf3, t3, af); af = fma4(wf4, t4, af);
            float4 ag = fma4(wg0, hw, f4(gbv));
            ag = fma4(wg1, t1, ag); ag = fma4(wg2, t2, ag);
            ag = fma4(wg3, t3, ag); ag = fma4(wg4, t4, ag);
            float4 o;
            o.x = gate1(af.x, ag.x);
            o.y = gate1(af.y, ag.y);
            o.z = gate1(af.z, ag.z);
            o.w = gate1(af.w, ag.w);
            float4 nh = resid4(rwv, o, hw, rbv);
            if (w == 0 && first) nh = f4(0.0f);   // keep t<0 padding exactly 0
            h[w] = nh;
            if (w == 1) sk1 = add4(sk1, o);
            if (w == 2) sk2 = add4(sk2, o);
        }
        if (k < 9) {       // last layer's h never re-read from LDS
            __syncthreads();
            #pragma unroll
            for (int w = 0; w < NGROUPW; ++w) st4(&lds[4 * (tid + w * NTHREADS)], h[w]);
            __syncthreads();
        }
    }

    if (STAGE < 2) {
        st4(hout + rowbase + base_t + 4 * tid, h[1]);
        st4(hout + rowbase + base_t + 4096 + 4 * tid, h[2]);
        st4(skio + rowbase + base_t + 4 * tid, sk1);
        st4(skio + rowbase + base_t + 4096 + 4 * tid, sk2);
    } else {
        // fused epilogue + per-block (max, sum-exp) stats
        const float c1wv = c1w[0], c1bv = c1b[0], c2wv = c2w[0], c2bv = c2b[0];
        float4 p1, p2;
        p1.x = mulaw(sk1.x, c1wv, c1bv, c2wv, c2bv);
        p1.y = mulaw(sk1.y, c1wv, c1bv, c2wv, c2bv);
        p1.z = mulaw(sk1.z, c1wv, c1bv, c2wv, c2bv);
        p1.w = mulaw(sk1.w, c1wv, c1bv, c2wv, c2bv);
        p2.x = mulaw(sk2.x, c1wv, c1bv, c2wv, c2bv);
        p2.y = mulaw(sk2.y, c1wv, c1bv, c2wv, c2bv);
        p2.z = mulaw(sk2.z, c1wv, c1bv, c2wv, c2bv);
        p2.w = mulaw(sk2.w, c1wv, c1bv, c2wv, c2bv);
        st4(skio + rowbase + base_t + 4 * tid, p1);
        st4(skio + rowbase + base_t + 4096 + 4 * tid, p2);

        float pmax = fmaxf(fmaxf(fmaxf(p1.x, p1.y), fmaxf(p1.z, p1.w)),
                           fmaxf(fmaxf(p2.x, p2.y), fmaxf(p2.z, p2.w)));
        #pragma unroll
        for (int off = 32; off; off >>= 1) pmax = fmaxf(pmax, __shfl_xor(pmax, off, 64));
        if ((tid & 63) == 0) red[tid >> 6] = pmax;
        __syncthreads();
        float bmax = red[0];
        #pragma unroll
        for (int i = 1; i < NTHREADS / 64; ++i) bmax = fmaxf(bmax, red[i]);
        __syncthreads();   // red reused below

        float ps = fexp2((p1.x - bmax) * LOG2E) + fexp2((p1.y - bmax) * LOG2E)
                 + fexp2((p1.z - bmax) * LOG2E) + fexp2((p1.w - bmax) * LOG2E)
                 + fexp2((p2.x - bmax) * LOG2E) + fexp2((p2.y - bmax) * LOG2E)
                 + fexp2((p2.z - bmax) * LOG2E) + fexp2((p2.w - bmax) * LOG2E);
        #pragma unroll
        for (int off = 32; off; off >>= 1) ps += __shfl_xor(ps, off, 64);
        if ((tid & 63) == 0) red[tid >> 6] = ps;
        __syncthreads();
        if (tid == 0) {
            float s = 0.0f;
            #pragma unroll
            for (int i = 0; i < NTHREADS / 64; ++i) s += red[i];
            blockstats[bid] = make_float2(bmax, s);
        }
    }
}

// 8 blocks (one per row) x 64 threads: reduce 32 block-stats -> (rowmax, 1/rowsum)
__global__ __launch_bounds__(64)
void combine_kernel(const float2* __restrict__ bs, float2* __restrict__ rs)
{
    const int row = blockIdx.x;
    const int lane = threadIdx.x;
    float bm = -3.0e38f, s = 0.0f;
    if (lane < CHUNKS_PER_ROW) {
        float2 v = bs[row * CHUNKS_PER_ROW + lane];
        bm = v.x; s = v.y;
    }
    float m = bm;
    #pragma unroll
    for (int off = 32; off; off >>= 1) m = fmaxf(m, __shfl_xor(m, off, 64));
    float c = s * fexp2((bm - m) * LOG2E);
    #pragma unroll
    for (int off = 32; off; off >>= 1) c += __shfl_xor(c, off, 64);
    if (lane == 0) rs[row] = make_float2(m, 1.0f / c);
}

__global__ __launch_bounds__(NTHREADS)
void norm_kernel(float* __restrict__ p, const float2* __restrict__ rs)
{
    const int tid = threadIdx.x, bid = blockIdx.x;
    const int row = bid / CHUNKS_PER_ROW;
    const float2 st = rs[row];
    const int base = row * T_LEN + (bid % CHUNKS_PER_ROW) * CHUNK + 4 * tid;
    #pragma unroll
    for (int part = 0; part < 2; ++part) {
        float* q = p + base + part * 4096;
        float4 v = ld4(q);
        v.x = fexp2((v.x - st.x) * LOG2E) * st.y;
        v.y = fexp2((v.y - st.x) * LOG2E) * st.y;
        v.z = fexp2((v.z - st.x) * LOG2E) * st.y;
        v.w = fexp2((v.w - st.x) * LOG2E) * st.y;
        st4(q, v);
    }
}

extern "C" void kernel_launch(void* const* d_in, const int* in_sizes, int n_in,
                              void* d_out, int out_size, void* d_ws, size_t ws_size,
                              hipStream_t stream)
{
    (void)in_sizes; (void)n_in; (void)out_size; (void)ws_size;
    const float* x   = (const float*)d_in[0];
    const float* cw  = (const float*)d_in[1];
    const float* cb  = (const float*)d_in[2];
    const float* fw  = (const float*)d_in[3];
    const float* fb  = (const float*)d_in[4];
    const float* gw  = (const float*)d_in[5];
    const float* gb  = (const float*)d_in[6];
    const float* rw  = (const float*)d_in[7];
    const float* rb  = (const float*)d_in[8];
    const float* c1w = (const float*)d_in[9];
    const float* c1b = (const float*)d_in[10];
    const float* c2w = (const float*)d_in[11];
    const float* c2b = (const float*)d_in[12];
    float* out = (float*)d_out;

    const size_t NTOT = (size_t)B_SZ * T_LEN;
    float*  hA = (float*)d_ws;                                    // 8 MB
    float*  hB = (float*)((char*)d_ws + NTOT * 4);                // 8 MB
    float2* bs = (float2*)((char*)d_ws + 2 * NTOT * 4);           // 2 KB
    float2* rs = (float2*)((char*)d_ws + 2 * NTOT * 4 + 4096);    // 64 B

    // d_out doubles as the skip accumulator between stages, then holds
    // pre-softmax values, then the final softmax output.
    stage_kernel<0><<<NBLOCKS, NTHREADS, 0, stream>>>(x,  cw, cb, fw, fb, gw, gb, rw, rb,
                                                      hA, out, c1w, c1b, c2w, c2b, bs);
    stage_kernel<1><<<NBLOCKS, NTHREADS, 0, stream>>>(hA, cw, cb, fw, fb, gw, gb, rw, rb,
                                                      hB, out, c1w, c1b, c2w, c2b, bs);
    stage_kernel<2><<<NBLOCKS, NTHREADS, 0, stream>>>(hB, cw, cb, fw, fb, gw, gb, rw, rb,
                                                      nullptr, out, c1w, c1b, c2w, c2b, bs);
    combine_kernel<<<B_SZ, 64, 0, stream>>>(bs, rs);
    norm_kernel<<<NBLOCKS, NTHREADS, 0, stream>>>(out, rs);
}

// Round 4
// 85.042 us; speedup vs baseline: 1.7890x; 1.1228x over previous
//
#include <hip/hip_runtime.h>

#define T_LEN 262144
#define B_SZ 8
#define CHUNK 8192
#define HALO 4096
#define NTHREADS 1024
#define NGROUPW 3                      // float4 groups per thread: 12288/4/1024
#define NGROUPS ((CHUNK + HALO) / 4)   // 3072
#define CHUNKS_PER_ROW (T_LEN / CHUNK) // 32
#define NBLOCKS (B_SZ * CHUNKS_PER_ROW)
#define LOG2E 1.4426950408889634f
#define NEG2LOG2E (-2.8853900817779268f)
#define NEGLOG2E  (-1.4426950408889634f)

__device__ __forceinline__ float frcp(float x)  { return __builtin_amdgcn_rcpf(x); }
__device__ __forceinline__ float fexp2(float x) { return __builtin_amdgcn_exp2f(x); }
__device__ __forceinline__ float4 ld4(const float* p) { return *(const float4*)p; }
__device__ __forceinline__ void st4(float* p, float4 v) { *(float4*)p = v; }
__device__ __forceinline__ float4 f4(float v) { return make_float4(v, v, v, v); }
__device__ __forceinline__ float4 fma4(float a, float4 b, float4 c) {
    return make_float4(__builtin_fmaf(a, b.x, c.x), __builtin_fmaf(a, b.y, c.y),
                       __builtin_fmaf(a, b.z, c.z), __builtin_fmaf(a, b.w, c.w));
}
__device__ __forceinline__ float4 add4(float4 a, float4 b) {
    return make_float4(a.x + b.x, a.y + b.y, a.z + b.z, a.w + b.w);
}
// o = tanh(a)*sigmoid(b) with af = -2*log2e*a, ag = -log2e*b pre-scaled:
// E1=2^af=e^{-2a}, E2=2^ag=e^{-b}; o = (1-E1) / ((1+E1)(1+E2))
__device__ __forceinline__ float gate1(float af, float ag) {
    float E1 = fexp2(af), E2 = fexp2(ag);
    float d1 = 1.0f + E1;
    float den = __builtin_fmaf(E2, d1, d1);
    return (1.0f - E1) * frcp(den);
}
__device__ __forceinline__ float4 resid4(float rwv, float4 o, float4 hw, float rbv) {
    return make_float4(__builtin_fmaf(rwv, o.x, hw.x + rbv), __builtin_fmaf(rwv, o.y, hw.y + rbv),
                       __builtin_fmaf(rwv, o.z, hw.z + rbv), __builtin_fmaf(rwv, o.w, hw.w + rbv));
}
// conv1->relu->conv2->relu->mu-law expand; exp(|b|*ln256) == exp2(|b|*8)
__device__ __forceinline__ float mulaw(float v, float c1wv, float c1bv, float c2wv, float c2bv) {
    float a  = __builtin_fmaf(c1wv, fmaxf(v, 0.0f), c1bv);
    float b2 = __builtin_fmaf(c2wv, fmaxf(a, 0.0f), c2bv);
    float m  = fexp2(fabsf(b2) * 8.0f) - 1.0f;
    return copysignf(m * (1.0f / 255.0f), b2);
}
// bf16x2 pack (truncating) / unpack ("noisy" high half: low mantissa bits keep
// the neighbor's bits -- <=2^-9 relative noise, same order as bf16 rounding).
__device__ __forceinline__ uint2 pk4(float4 v) {
    uint2 u;
    u.x = (__float_as_uint(v.y) & 0xffff0000u) | (__float_as_uint(v.x) >> 16);
    u.y = (__float_as_uint(v.w) & 0xffff0000u) | (__float_as_uint(v.z) >> 16);
    return u;
}
__device__ __forceinline__ float4 up4(uint2 u) {
    return make_float4(__uint_as_float(u.x << 16), __uint_as_float(u.x),
                       __uint_as_float(u.y << 16), __uint_as_float(u.y));
}

// One dilation cycle (10 layers, d=1..512). Thread owns 3 float4 groups IN
// REGISTERS (fp32) across all layers; LDS holds bf16x2-packed h for cross-
// thread taps, double-buffered: layer reads buf[c] (b64), writes buf[c^1],
// ONE barrier per layer. Zero-padding: global t<0 <=> (chunk==0 && w==0).
template <int STAGE>
__global__ __launch_bounds__(NTHREADS, 4)
void stage_kernel(const float* __restrict__ in,
                  const float* __restrict__ cw, const float* __restrict__ cb,
                  const float* __restrict__ fw, const float* __restrict__ fb,
                  const float* __restrict__ gw, const float* __restrict__ gb,
                  const float* __restrict__ rw, const float* __restrict__ rb,
                  float* __restrict__ hout, float* __restrict__ skio,
                  const float* __restrict__ c1w, const float* __restrict__ c1b,
                  const float* __restrict__ c2w, const float* __restrict__ c2b,
                  float2* __restrict__ blockstats)
{
    __shared__ uint2 bufl[2][NGROUPS];       // 2 x 24 KB bf16x2 tap buffers
    __shared__ float red[NTHREADS / 64];

    const int tid = threadIdx.x;
    const int bid = blockIdx.x;
    const int row = bid / CHUNKS_PER_ROW;
    const int chunk = bid % CHUNKS_PER_ROW;
    const int rowbase = row * T_LEN;
    const int base_t = chunk * CHUNK;
    const bool first = (chunk == 0);
    const float* inb = in + rowbase + base_t - HALO;

    // ---- load own groups (fp32 regs) + publish bf16 to buf 0 ----
    float4 h[NGROUPW];
    #pragma unroll
    for (int w = 0; w < NGROUPW; ++w) {
        int G = tid + w * NTHREADS;
        if (w == 0 && first) h[w] = f4(0.0f);
        else                 h[w] = ld4(inb + 4 * G);
        bufl[0][G] = pk4(h[w]);
    }
    float4 sk1, sk2;   // skip accumulators for w=1,2 (valid region)
    if (STAGE == 0) { sk1 = f4(0.0f); sk2 = f4(0.0f); }
    else {
        sk1 = ld4(skio + rowbase + base_t + 4 * tid);
        sk2 = ld4(skio + rowbase + base_t + 4096 + 4 * tid);
    }
    __syncthreads();

    int c = 0;
    if (STAGE == 0) {
        // causal conv (d=1); weight for tap distance m is cw[4-m]
        const float c0 = cw[4], c1 = cw[3], c2 = cw[2], c3 = cw[1], c4 = cw[0];
        const float bb = cb[0];
        #pragma unroll
        for (int w = 0; w < NGROUPW; ++w) {
            int G = tid + w * NTHREADS;
            int gm = G - 1; if (w == 0) gm = gm < 0 ? 0 : gm;   // junk-in-halo OK
            float4 T = up4(bufl[0][gm]);
            float4 hw = h[w];
            float4 t1 = make_float4(T.w, hw.x, hw.y, hw.z);
            float4 t2 = make_float4(T.z, T.w, hw.x, hw.y);
            float4 t3 = make_float4(T.y, T.z, T.w, hw.x);
            float4 t4 = make_float4(T.x, T.y, T.z, T.w);
            float4 acc = fma4(c0, hw, f4(bb));
            acc = fma4(c1, t1, acc);
            acc = fma4(c2, t2, acc);
            acc = fma4(c3, t3, acc);
            acc = fma4(c4, t4, acc);
            if (w == 0 && first) acc = f4(0.0f);
            h[w] = acc;
            bufl[1][G] = pk4(acc);
        }
        __syncthreads();
        c = 1;
    }

    // ---- 10 dilated gated layers, one barrier each ----
    #pragma unroll
    for (int k = 0; k < 10; ++k) {
        const int d = 1 << k;
        const int L = STAGE * 10 + k;
        const float* fwL = fw + 5 * L;
        const float* gwL = gw + 5 * L;
        const float wf0 = fwL[4] * NEG2LOG2E, wf1 = fwL[3] * NEG2LOG2E,
                    wf2 = fwL[2] * NEG2LOG2E, wf3 = fwL[1] * NEG2LOG2E,
                    wf4 = fwL[0] * NEG2LOG2E;
        const float wg0 = gwL[4] * NEGLOG2E, wg1 = gwL[3] * NEGLOG2E,
                    wg2 = gwL[2] * NEGLOG2E, wg3 = gwL[1] * NEGLOG2E,
                    wg4 = gwL[0] * NEGLOG2E;
        const float fbv = fb[L] * NEG2LOG2E, gbv = gb[L] * NEGLOG2E;
        const float rwv = rw[L], rbv = rb[L];

        #pragma unroll
        for (int w = 0; w < NGROUPW; ++w) {
            const int G = tid + w * NTHREADS;
            float4 hw = h[w];
            float4 t1, t2, t3, t4;
            if (d >= 4) {
                const int DG = d >> 2;           // taps stay group-aligned
                int g1 = G - DG, g2 = G - 2 * DG, g3 = G - 3 * DG, g4 = G - 4 * DG;
                if (w == 0) {                    // only halo groups can underflow
                    g1 = g1 < 0 ? 0 : g1; g2 = g2 < 0 ? 0 : g2;
                    g3 = g3 < 0 ? 0 : g3; g4 = g4 < 0 ? 0 : g4;
                }
                t1 = up4(bufl[c][g1]);
                t2 = up4(bufl[c][g2]);
                t3 = up4(bufl[c][g3]);
                t4 = up4(bufl[c][g4]);
            } else if (d == 1) {
                int gm = G - 1; if (w == 0) gm = gm < 0 ? 0 : gm;
                float4 T = up4(bufl[c][gm]);
                t1 = make_float4(T.w, hw.x, hw.y, hw.z);
                t2 = make_float4(T.z, T.w, hw.x, hw.y);
                t3 = make_float4(T.y, T.z, T.w, hw.x);
                t4 = make_float4(T.x, T.y, T.z, T.w);
            } else { // d == 2
                int gm1 = G - 1, gm2 = G - 2;
                if (w == 0) { gm1 = gm1 < 0 ? 0 : gm1; gm2 = gm2 < 0 ? 0 : gm2; }
                float4 T1 = up4(bufl[c][gm1]);
                float4 T2 = up4(bufl[c][gm2]);
                t1 = make_float4(T1.z, T1.w, hw.x, hw.y);
                t2 = T1;
                t3 = make_float4(T2.z, T2.w, T1.x, T1.y);
                t4 = T2;
            }
            float4 af = fma4(wf0, hw, f4(fbv));
            af = fma4(wf1, t1, af); af = fma4(wf2, t2, af);
            af = fma4(wf3, t3, af); af = fma4(wf4, t4, af);
            float4 ag = fma4(wg0, hw, f4(gbv));
            ag = fma4(wg1, t1, ag); ag = fma4(wg2, t2, ag);
            ag = fma4(wg3, t3, ag); ag = fma4(wg4, t4, ag);
            float4 o;
            o.x = gate1(af.x, ag.x);
            o.y = gate1(af.y, ag.y);
            o.z = gate1(af.z, ag.z);
            o.w = gate1(af.w, ag.w);
            float4 nh = resid4(rwv, o, hw, rbv);
            if (w == 0 && first) nh = f4(0.0f);   // keep t<0 padding exactly 0
            h[w] = nh;
            if (k < 9) bufl[c ^ 1][G] = pk4(nh);  // last layer never re-read
            if (w == 1) sk1 = add4(sk1, o);
            if (w == 2) sk2 = add4(sk2, o);
        }
        if (k < 9) __syncthreads();
        c ^= 1;
    }

    if (STAGE < 2) {
        st4(hout + rowbase + base_t + 4 * tid, h[1]);
        st4(hout + rowbase + base_t + 4096 + 4 * tid, h[2]);
        st4(skio + rowbase + base_t + 4 * tid, sk1);
        st4(skio + rowbase + base_t + 4096 + 4 * tid, sk2);
    } else {
        // fused epilogue + per-block (max, sum-exp) stats
        const float c1wv = c1w[0], c1bv = c1b[0], c2wv = c2w[0], c2bv = c2b[0];
        float4 p1, p2;
        p1.x = mulaw(sk1.x, c1wv, c1bv, c2wv, c2bv);
        p1.y = mulaw(sk1.y, c1wv, c1bv, c2wv, c2bv);
        p1.z = mulaw(sk1.z, c1wv, c1bv, c2wv, c2bv);
        p1.w = mulaw(sk1.w, c1wv, c1bv, c2wv, c2bv);
        p2.x = mulaw(sk2.x, c1wv, c1bv, c2wv, c2bv);
        p2.y = mulaw(sk2.y, c1wv, c1bv, c2wv, c2bv);
        p2.z = mulaw(sk2.z, c1wv, c1bv, c2wv, c2bv);
        p2.w = mulaw(sk2.w, c1wv, c1bv, c2wv, c2bv);
        st4(skio + rowbase + base_t + 4 * tid, p1);
        st4(skio + rowbase + base_t + 4096 + 4 * tid, p2);

        float pmax = fmaxf(fmaxf(fmaxf(p1.x, p1.y), fmaxf(p1.z, p1.w)),
                           fmaxf(fmaxf(p2.x, p2.y), fmaxf(p2.z, p2.w)));
        #pragma unroll
        for (int off = 32; off; off >>= 1) pmax = fmaxf(pmax, __shfl_xor(pmax, off, 64));
        if ((tid & 63) == 0) red[tid >> 6] = pmax;
        __syncthreads();
        float bmax = red[0];
        #pragma unroll
        for (int i = 1; i < NTHREADS / 64; ++i) bmax = fmaxf(bmax, red[i]);
        __syncthreads();   // red reused below

        float ps = fexp2((p1.x - bmax) * LOG2E) + fexp2((p1.y - bmax) * LOG2E)
                 + fexp2((p1.z - bmax) * LOG2E) + fexp2((p1.w - bmax) * LOG2E)
                 + fexp2((p2.x - bmax) * LOG2E) + fexp2((p2.y - bmax) * LOG2E)
                 + fexp2((p2.z - bmax) * LOG2E) + fexp2((p2.w - bmax) * LOG2E);
        #pragma unroll
        for (int off = 32; off; off >>= 1) ps += __shfl_xor(ps, off, 64);
        if ((tid & 63) == 0) red[tid >> 6] = ps;
        __syncthreads();
        if (tid == 0) {
            float s = 0.0f;
            #pragma unroll
            for (int i = 0; i < NTHREADS / 64; ++i) s += red[i];
            blockstats[bid] = make_float2(bmax, s);
        }
    }
}

// 8 blocks (one per row) x 64 threads: reduce 32 block-stats -> (rowmax, 1/rowsum)
__global__ __launch_bounds__(64)
void combine_kernel(const float2* __restrict__ bs, float2* __restrict__ rs)
{
    const int row = blockIdx.x;
    const int lane = threadIdx.x;
    float bm = -3.0e38f, s = 0.0f;
    if (lane < CHUNKS_PER_ROW) {
        float2 v = bs[row * CHUNKS_PER_ROW + lane];
        bm = v.x; s = v.y;
    }
    float m = bm;
    #pragma unroll
    for (int off = 32; off; off >>= 1) m = fmaxf(m, __shfl_xor(m, off, 64));
    float c = s * fexp2((bm - m) * LOG2E);
    #pragma unroll
    for (int off = 32; off; off >>= 1) c += __shfl_xor(c, off, 64);
    if (lane == 0) rs[row] = make_float2(m, 1.0f / c);
}

__global__ __launch_bounds__(NTHREADS)
void norm_kernel(float* __restrict__ p, const float2* __restrict__ rs)
{
    const int tid = threadIdx.x, bid = blockIdx.x;
    const int row = bid / CHUNKS_PER_ROW;
    const float2 st = rs[row];
    const int base = row * T_LEN + (bid % CHUNKS_PER_ROW) * CHUNK + 4 * tid;
    #pragma unroll
    for (int part = 0; part < 2; ++part) {
        float* q = p + base + part * 4096;
        float4 v = ld4(q);
        v.x = fexp2((v.x - st.x) * LOG2E) * st.y;
        v.y = fexp2((v.y - st.x) * LOG2E) * st.y;
        v.z = fexp2((v.z - st.x) * LOG2E) * st.y;
        v.w = fexp2((v.w - st.x) * LOG2E) * st.y;
        st4(q, v);
    }
}

extern "C" void kernel_launch(void* const* d_in, const int* in_sizes, int n_in,
                              void* d_out, int out_size, void* d_ws, size_t ws_size,
                              hipStream_t stream)
{
    (void)in_sizes; (void)n_in; (void)out_size; (void)ws_size;
    const float* x   = (const float*)d_in[0];
    const float* cw  = (const float*)d_in[1];
    const float* cb  = (const float*)d_in[2];
    const float* fw  = (const float*)d_in[3];
    const float* fb  = (const float*)d_in[4];
    const float* gw  = (const float*)d_in[5];
    const float* gb  = (const float*)d_in[6];
    const float* rw  = (const float*)d_in[7];
    const float* rb  = (const float*)d_in[8];
    const float* c1w = (const float*)d_in[9];
    const float* c1b = (const float*)d_in[10];
    const float* c2w = (const float*)d_in[11];
    const float* c2b = (const float*)d_in[12];
    float* out = (float*)d_out;

    const size_t NTOT = (size_t)B_SZ * T_LEN;
    float*  hA = (float*)d_ws;                                    // 8 MB
    float*  hB = (float*)((char*)d_ws + NTOT * 4);                // 8 MB
    float2* bs = (float2*)((char*)d_ws + 2 * NTOT * 4);           // 2 KB
    float2* rs = (float2*)((char*)d_ws + 2 * NTOT * 4 + 4096);    // 64 B

    // d_out doubles as the skip accumulator between stages, then holds
    // pre-softmax values, then the final softmax output.
    stage_kernel<0><<<NBLOCKS, NTHREADS, 0, stream>>>(x,  cw, cb, fw, fb, gw, gb, rw, rb,
                                                      hA, out, c1w, c1b, c2w, c2b, bs);
    stage_kernel<1><<<NBLOCKS, NTHREADS, 0, stream>>>(hA, cw, cb, fw, fb, gw, gb, rw, rb,
                                                      hB, out, c1w, c1b, c2w, c2b, bs);
    stage_kernel<2><<<NBLOCKS, NTHREADS, 0, stream>>>(hB, cw, cb, fw, fb, gw, gb, rw, rb,
                                                      nullptr, out, c1w, c1b, c2w, c2b, bs);
    combine_kernel<<<B_SZ, 64, 0, stream>>>(bs, rs);
    norm_kernel<<<NBLOCKS, NTHREADS, 0, stream>>>(out, rs);
}